// Round 1
// baseline (289.855 us; speedup 1.0000x reference)
//
#include <hip/hip_runtime.h>
#include <hip/hip_bf16.h>
#include <cstdint>
#include <cstddef>

#define B_  64
#define T_  256
#define C_  2048
#define HS_ 128
#define N_  384

typedef __bf16 bf16x8 __attribute__((ext_vector_type(8)));
typedef float  floatx4 __attribute__((ext_vector_type(4)));

__device__ __forceinline__ unsigned short f2bf_rne(float f) {
  union { float f; unsigned int u; } v; v.f = f;
  unsigned int r = v.u + 0x7fffu + ((v.u >> 16) & 1u);
  return (unsigned short)(r >> 16);
}
__device__ __forceinline__ unsigned short f2bf(float f) {
  union { float f; unsigned int u; } v; v.f = f;
  return (unsigned short)((v.u + 0x8000u) >> 16);
}

__device__ __forceinline__ void async_copy16(const void* g, void* l) {
  __builtin_amdgcn_global_load_lds(
      (const __attribute__((address_space(1))) unsigned int*)g,
      (__attribute__((address_space(3))) unsigned int*)l, 16, 0, 0);
}

__device__ __forceinline__ bf16x8 cvt8(const float4& a, const float4& b) {
  union { unsigned short u[8]; bf16x8 v; } r;
  r.u[0] = f2bf(a.x); r.u[1] = f2bf(a.y); r.u[2] = f2bf(a.z); r.u[3] = f2bf(a.w);
  r.u[4] = f2bf(b.x); r.u[5] = f2bf(b.y); r.u[6] = f2bf(b.z); r.u[7] = f2bf(b.w);
  return r.v;
}

// ---------------- Weight transpose + bf16 cast: Wt[w*128+h][c] = W_w[c][h] ---
__global__ __launch_bounds__(256) void wt_kernel(
    const float* __restrict__ Wk, const float* __restrict__ Wq,
    const float* __restrict__ Wv, unsigned short* __restrict__ Wt) {
  __shared__ float tile[32][33];
  const int w  = blockIdx.z;
  const int c0 = blockIdx.x * 32;
  const int h0 = blockIdx.y * 32;
  const float* W = (w == 0) ? Wk : (w == 1) ? Wq : Wv;
  const int tx = threadIdx.x & 31, ty = threadIdx.x >> 5;
#pragma unroll
  for (int i = 0; i < 32; i += 8)
    tile[ty + i][tx] = W[(size_t)(c0 + ty + i) * HS_ + h0 + tx];
  __syncthreads();
#pragma unroll
  for (int i = 0; i < 32; i += 8) {
    int hh = ty + i, cc = tx;
    Wt[(size_t)(w * HS_ + h0 + hh) * C_ + c0 + cc] = f2bf_rne(tile[cc][hh]);
  }
}

// ---------------- QKV GEMM: BM=64 x BN=384 (full N), BK=32 ------------------
// 512 threads = 8 waves (2m x 4n), wave tile 32x96. grid=256 = 1 block/CU.
// X (fp32) is read EXACTLY ONCE: A goes global->register (2-iteration
// prefetch, double register set) and is converted to bf16 in-register — no
// A LDS round-trip, no per-n-tile re-read, no conflicted As stores.
// B (bf16 Wt, L2-resident) is double-buffered in LDS via global_load_lds;
// one barrier per K-step, DMA drained at the NEXT K-step's barrier.
__global__ __launch_bounds__(512) void qkv_gemm(
    const float* __restrict__ X, const unsigned short* __restrict__ Wt,
    unsigned short* __restrict__ kqv, unsigned short* __restrict__ vT) {
  __shared__ unsigned short Bs[2][N_ * 32];   // 2 x 24 KB = 48 KB

  const int tid  = threadIdx.x;
  const int wave = tid >> 6, lane = tid & 63;
  const int quad = lane >> 4, l16 = lane & 15;

  const int m0 = blockIdx.x * 64;
  const int wm = (wave >> 2) * 32;   // 2 m-groups of waves
  const int wn = (wave & 3) * 96;    // 4 n-groups of waves

  // B DMA mapping: slot s = r*512+tid -> row n = s>>2, 16B-chunk c = s&3.
  // Row is 64 B so even/odd rows alternate bank halves: reads are already
  // uniformly bank-spread; LDS layout stays linear (global_load_lds rule).
  int dn[3], dc[3], ddst[3];
#pragma unroll
  for (int r = 0; r < 3; ++r) {
    int s = r * 512 + tid;
    dn[r]   = s >> 2;
    dc[r]   = s & 3;
    ddst[r] = (r * 512 + wave * 64) * 8;   // wave-uniform LDS base (shorts)
  }

  // A row pointers: this lane covers rows (wm+l16) and (wm+16+l16),
  // k-chunk quad*8 .. quad*8+7 within each 32-wide K-step.
  const float* xr0 = X + (size_t)(m0 + wm + l16) * C_ + quad * 8;
  const float* xr1 = xr0 + (size_t)16 * C_;

  // ---- prologue: B_0 DMA + A registers for k=0 and k=1 (2-deep prefetch)
#pragma unroll
  for (int r = 0; r < 3; ++r)
    async_copy16(Wt + (size_t)dn[r] * C_ + dc[r] * 8, &Bs[0][ddst[r]]);
  float4 ava[4], avb[4];
  ava[0] = *(const float4*)(xr0);
  ava[1] = *(const float4*)(xr0 + 4);
  ava[2] = *(const float4*)(xr1);
  ava[3] = *(const float4*)(xr1 + 4);
  avb[0] = *(const float4*)(xr0 + 32);
  avb[1] = *(const float4*)(xr0 + 36);
  avb[2] = *(const float4*)(xr1 + 32);
  avb[3] = *(const float4*)(xr1 + 36);

  floatx4 acc[2][6] = {};

  for (int k = 0; k < 64; k += 2) {
    // ======== sub-iter A: K-step k, uses Bs[0], ava ========
    {
      bf16x8 af0 = cvt8(ava[0], ava[1]);
      bf16x8 af1 = cvt8(ava[2], ava[3]);
      __syncthreads();                      // drains Bs[0] DMA
      {                                     // issue DMA for k+1 -> Bs[1]
        const int kn = (k + 1) * 32;
#pragma unroll
        for (int r = 0; r < 3; ++r)
          async_copy16(Wt + (size_t)dn[r] * C_ + kn + dc[r] * 8, &Bs[1][ddst[r]]);
      }
      if (k + 2 < 64) {                     // refill ava for k+2
        const int kn = (k + 2) * 32;
        ava[0] = *(const float4*)(xr0 + kn);
        ava[1] = *(const float4*)(xr0 + kn + 4);
        ava[2] = *(const float4*)(xr1 + kn);
        ava[3] = *(const float4*)(xr1 + kn + 4);
      }
#pragma unroll
      for (int nt = 0; nt < 6; ++nt) {
        const int n = wn + nt * 16 + l16;
        bf16x8 bv = *(const bf16x8*)&Bs[0][n * 32 + quad * 8];
        acc[0][nt] = __builtin_amdgcn_mfma_f32_16x16x32_bf16(af0, bv, acc[0][nt], 0, 0, 0);
        acc[1][nt] = __builtin_amdgcn_mfma_f32_16x16x32_bf16(af1, bv, acc[1][nt], 0, 0, 0);
      }
    }
    // ======== sub-iter B: K-step k+1, uses Bs[1], avb ========
    {
      bf16x8 af0 = cvt8(avb[0], avb[1]);
      bf16x8 af1 = cvt8(avb[2], avb[3]);
      __syncthreads();                      // drains Bs[1] DMA
      if (k + 2 < 64) {                     // issue DMA for k+2 -> Bs[0]
        const int kn = (k + 2) * 32;
#pragma unroll
        for (int r = 0; r < 3; ++r)
          async_copy16(Wt + (size_t)dn[r] * C_ + kn + dc[r] * 8, &Bs[0][ddst[r]]);
      }
      if (k + 3 < 64) {                     // refill avb for k+3
        const int kn = (k + 3) * 32;
        avb[0] = *(const float4*)(xr0 + kn);
        avb[1] = *(const float4*)(xr0 + kn + 4);
        avb[2] = *(const float4*)(xr1 + kn);
        avb[3] = *(const float4*)(xr1 + kn + 4);
      }
#pragma unroll
      for (int nt = 0; nt < 6; ++nt) {
        const int n = wn + nt * 16 + l16;
        bf16x8 bv = *(const bf16x8*)&Bs[1][n * 32 + quad * 8];
        acc[0][nt] = __builtin_amdgcn_mfma_f32_16x16x32_bf16(af0, bv, acc[0][nt], 0, 0, 0);
        acc[1][nt] = __builtin_amdgcn_mfma_f32_16x16x32_bf16(af1, bv, acc[1][nt], 0, 0, 0);
      }
    }
  }

  // ---- epilogue: C/D layout col=lane&15, row=quad*4+reg
#pragma unroll
  for (int mt = 0; mt < 2; ++mt)
#pragma unroll
    for (int nt = 0; nt < 6; ++nt) {
      const int colb = wn + nt * 16;
#pragma unroll
      for (int r = 0; r < 4; ++r) {
        int row = m0 + wm + mt * 16 + quad * 4 + r;
        int col = colb + l16;
        unsigned short us = f2bf(acc[mt][nt][r]);
        kqv[(size_t)row * N_ + col] = us;
        if (colb >= 256) {   // V part -> also store transposed
          int bb = row >> 8, tt = row & 255;
          vT[(size_t)bb * HS_ * T_ + (size_t)(col - 256) * T_ + tt] = us;
        }
      }
    }
}

// ---------------- Attention: 4 waves/block, 2 waves per 16-row t-tile -------
// Wave (tile, par): handles s-tiles st with st&1==par, packed densely in its
// private P buffer. Partial O (unnormalized) + partial rowsum combined in LDS.
__global__ __launch_bounds__(256) void attn_kernel(
    const unsigned short* __restrict__ kqv, const unsigned short* __restrict__ vT,
    float* __restrict__ out) {
  __shared__ unsigned short P[4][16 * 136];  // 17.4 KB, per-wave packed P
  __shared__ float Olds[2][16][132];         // 16.9 KB (pad 132)
  __shared__ float rs1[2][16];

  const int tid  = threadIdx.x;
  const int wave = tid >> 6, lane = tid & 63;
  const int quad = lane >> 4, l16 = lane & 15;
  const int tile = wave >> 1, par = wave & 1;
  const int tt = blockIdx.x * 2 + tile;      // 0..15
  const int b  = blockIdx.y;
  const int t0 = tt * 16;
  const float scale = 0.022097086912079612f; // 2048^-0.5
  const unsigned short* kq = kqv + (size_t)b * T_ * N_;

  // k fragments (A operand), rows t0..t0+15
  bf16x8 kf[4];
#pragma unroll
  for (int ks = 0; ks < 4; ++ks)
    kf[ks] = *(const bf16x8*)&kq[(size_t)(t0 + l16) * N_ + ks * 32 + quad * 8];

  const int n_my = ((tt + 1) + (1 - par)) >> 1;  // my s-tile count
  const int npad = (n_my + 1) & ~1;              // padded to even

  float rsum[4] = {0.f, 0.f, 0.f, 0.f};

  // ---- S = k q^T over my s-tiles, exp+mask, pack into P (manual prefetch)
  bf16x8 qf[4];
  if (n_my > 0) {
    const int st = par;
#pragma unroll
    for (int ks = 0; ks < 4; ++ks)
      qf[ks] = *(const bf16x8*)&kq[(size_t)(st * 16 + l16) * N_ + HS_ + ks * 32 + quad * 8];
  }
  for (int j = 0; j < n_my; ++j) {
    bf16x8 qn[4];
    if (j + 1 < n_my) {
      const int st = par + 2 * (j + 1);
#pragma unroll
      for (int ks = 0; ks < 4; ++ks)
        qn[ks] = *(const bf16x8*)&kq[(size_t)(st * 16 + l16) * N_ + HS_ + ks * 32 + quad * 8];
    }
    floatx4 a = {};
#pragma unroll
    for (int ks = 0; ks < 4; ++ks)
      a = __builtin_amdgcn_mfma_f32_16x16x32_bf16(kf[ks], qf[ks], a, 0, 0, 0);
    const int st = par + 2 * j;
    const int scol = st * 16 + l16;
#pragma unroll
    for (int r = 0; r < 4; ++r) {
      int trow = t0 + quad * 4 + r;
      float p = (scol <= trow) ? __expf(a[r] * scale) : 0.f;
      rsum[r] += p;
      P[wave][(quad * 4 + r) * 136 + j * 16 + l16] = f2bf(p);
    }
#pragma unroll
    for (int ks = 0; ks < 4; ++ks) qf[ks] = qn[ks];
  }
  if (npad > n_my) {  // zero-fill the odd tail tile
#pragma unroll
    for (int r = 0; r < 4; ++r)
      P[wave][(quad * 4 + r) * 136 + n_my * 16 + l16] = 0;
  }
  // row sums: reduce across the 16 lanes of each quad
#pragma unroll
  for (int m = 1; m < 16; m <<= 1)
#pragma unroll
    for (int r = 0; r < 4; ++r)
      rsum[r] += __shfl_xor(rsum[r], m, 64);

  // ---- O_partial = P @ V over packed k-steps (manual prefetch)
  floatx4 oacc[8] = {};
  const unsigned short* vb = vT + (size_t)b * HS_ * T_;
  const int nks = npad >> 1;
  const int sb_off = (quad >> 1);        // which packed 16-tile inside 32-k
  const int sb_lo  = (quad & 1) * 8;
  bf16x8 bv[8]; bf16x8 pa;
  if (nks > 0) {
    int st = par + 2 * (0 + sb_off);
    int sbase = st * 16 + sb_lo;
    pa = *(const bf16x8*)&P[wave][l16 * 136 + 0 * 32 + quad * 8];
#pragma unroll
    for (int nt = 0; nt < 8; ++nt)
      bv[nt] = *(const bf16x8*)&vb[(size_t)(nt * 16 + l16) * T_ + sbase];
  }
  for (int ks2 = 0; ks2 < nks; ++ks2) {
    bf16x8 bvn[8]; bf16x8 pan;
    if (ks2 + 1 < nks) {
      int jt = 2 * (ks2 + 1) + sb_off;
      int st = par + 2 * jt;
      int sbase = st * 16 + sb_lo;
      pan = *(const bf16x8*)&P[wave][l16 * 136 + (ks2 + 1) * 32 + quad * 8];
#pragma unroll
      for (int nt = 0; nt < 8; ++nt)
        bvn[nt] = *(const bf16x8*)&vb[(size_t)(nt * 16 + l16) * T_ + sbase];
    }
#pragma unroll
    for (int nt = 0; nt < 8; ++nt)
      oacc[nt] = __builtin_amdgcn_mfma_f32_16x16x32_bf16(pa, bv[nt], oacc[nt], 0, 0, 0);
    pa = pan;
#pragma unroll
    for (int nt = 0; nt < 8; ++nt) bv[nt] = bvn[nt];
  }

  // ---- combine partials across the two parity waves of each tile
  if (par == 1) {
#pragma unroll
    for (int nt = 0; nt < 8; ++nt)
#pragma unroll
      for (int r = 0; r < 4; ++r)
        Olds[tile][quad * 4 + r][nt * 16 + l16] = oacc[nt][r];
    if (l16 == 0) {
#pragma unroll
      for (int r = 0; r < 4; ++r) rs1[tile][quad * 4 + r] = rsum[r];
    }
  }
  __syncthreads();
  if (par == 0) {
    float inv[4];
#pragma unroll
    for (int r = 0; r < 4; ++r)
      inv[r] = 1.f / (rsum[r] + rs1[tile][quad * 4 + r]);
    float* ob = out + ((size_t)b * T_ + t0) * HS_;
#pragma unroll
    for (int nt = 0; nt < 8; ++nt)
#pragma unroll
      for (int r = 0; r < 4; ++r) {
        int row = quad * 4 + r;
        ob[(size_t)row * HS_ + nt * 16 + l16] =
            (oacc[nt][r] + Olds[tile][row][nt * 16 + l16]) * inv[r];
      }
  }
}

extern "C" void kernel_launch(void* const* d_in, const int* in_sizes, int n_in,
                              void* d_out, int out_size, void* d_ws, size_t ws_size,
                              hipStream_t stream) {
  const float* x  = (const float*)d_in[0];
  const float* Wk = (const float*)d_in[1];
  const float* Wq = (const float*)d_in[2];
  const float* Wv = (const float*)d_in[3];
  float* out = (float*)d_out;

  char* ws = (char*)d_ws;
  unsigned short* Wt  = (unsigned short*)(ws);                        // 1.5 MB
  unsigned short* kqv = (unsigned short*)(ws + 1572864);              // 12 MB
  unsigned short* vT  = (unsigned short*)(ws + 1572864 + 12582912);   // 4 MB

  hipLaunchKernelGGL(wt_kernel, dim3(64, 4, 3), dim3(256), 0, stream, Wk, Wq, Wv, Wt);
  hipLaunchKernelGGL(qkv_gemm, dim3(256), dim3(512), 0, stream, x, Wt, kqv, vT);
  hipLaunchKernelGGL(attn_kernel, dim3(8, 64), dim3(256), 0, stream, kqv, vT, out);
}

// Round 2
// 282.772 us; speedup vs baseline: 1.0250x; 1.0250x over previous
//
#include <hip/hip_runtime.h>
#include <hip/hip_bf16.h>
#include <cstdint>
#include <cstddef>

#define B_  64
#define T_  256
#define C_  2048
#define HS_ 128
#define N_  384

typedef __bf16 bf16x8 __attribute__((ext_vector_type(8)));
typedef float  floatx4 __attribute__((ext_vector_type(4)));

__device__ __forceinline__ unsigned short f2bf_rne(float f) {
  union { float f; unsigned int u; } v; v.f = f;
  unsigned int r = v.u + 0x7fffu + ((v.u >> 16) & 1u);
  return (unsigned short)(r >> 16);
}
__device__ __forceinline__ unsigned short f2bf(float f) {
  union { float f; unsigned int u; } v; v.f = f;
  return (unsigned short)((v.u + 0x8000u) >> 16);
}

__device__ __forceinline__ void async_copy16(const void* g, void* l) {
  __builtin_amdgcn_global_load_lds(
      (const __attribute__((address_space(1))) unsigned int*)g,
      (__attribute__((address_space(3))) unsigned int*)l, 16, 0, 0);
}

__device__ __forceinline__ bf16x8 cvt8(const float4& a, const float4& b) {
  union { unsigned short u[8]; bf16x8 v; } r;
  r.u[0] = f2bf(a.x); r.u[1] = f2bf(a.y); r.u[2] = f2bf(a.z); r.u[3] = f2bf(a.w);
  r.u[4] = f2bf(b.x); r.u[5] = f2bf(b.y); r.u[6] = f2bf(b.z); r.u[7] = f2bf(b.w);
  return r.v;
}

// ---------------- Weight transpose + bf16 cast: Wt[w*128+h][c] = W_w[c][h] ---
__global__ __launch_bounds__(256) void wt_kernel(
    const float* __restrict__ Wk, const float* __restrict__ Wq,
    const float* __restrict__ Wv, unsigned short* __restrict__ Wt) {
  __shared__ float tile[32][33];
  const int w  = blockIdx.z;
  const int c0 = blockIdx.x * 32;
  const int h0 = blockIdx.y * 32;
  const float* W = (w == 0) ? Wk : (w == 1) ? Wq : Wv;
  const int tx = threadIdx.x & 31, ty = threadIdx.x >> 5;
#pragma unroll
  for (int i = 0; i < 32; i += 8)
    tile[ty + i][tx] = W[(size_t)(c0 + ty + i) * HS_ + h0 + tx];
  __syncthreads();
#pragma unroll
  for (int i = 0; i < 32; i += 8) {
    int hh = ty + i, cc = tx;
    Wt[(size_t)(w * HS_ + h0 + hh) * C_ + c0 + cc] = f2bf_rne(tile[cc][hh]);
  }
}

// ---------------- QKV GEMM: 64m x 128n, BK=64, single-barrier pipeline ------
// Round-0 skeleton (grid 768 = 3 blocks/CU, 4 waves, xor-swizzled Bs DMA,
// one barrier per K-step) but with the A-LDS path DELETED: A rows are loaded
// per-wave as float4 directly from X (L3-resident) and converted to bf16
// fragments in-register. LDS pipe (the measured bottleneck: ~2400 cy of LDS
// traffic per 2125-cy K-step) drops to ~1540 cy/K-step: B frag reads + DMA
// writes only. Bit-identical math to round 0.
__global__ __launch_bounds__(256, 3) void qkv_gemm(
    const float* __restrict__ X, const unsigned short* __restrict__ Wt,
    unsigned short* __restrict__ kqv, unsigned short* __restrict__ vT) {
  __shared__ unsigned short Bs[2][128 * 64];   // 2 x 16 KB (xor-swizzled)

  const int tid  = threadIdx.x;
  const int wave = tid >> 6, lane = tid & 63;
  const int quad = lane >> 4, l16 = lane & 15;

  const int g  = blockIdx.x;
  const int ml = g & 7, q8 = g >> 3;
  const int nb = q8 % 3, mh = q8 / 3;
  const int m0 = (mh * 8 + ml) * 64;
  const int n0 = nb * 128;
  const int wm = (wave >> 1) * 32;
  const int wn = (wave & 1) * 64;

  // B DMA source mapping (implements the xor swizzle on the LDS side)
  int bsrc_n[4], bsrc_c[4], bdst[4];
#pragma unroll
  for (int r = 0; r < 4; ++r) {
    int slot = (r * 4 + wave) * 64 + lane;
    int n = slot >> 3, sl = slot & 7;
    bsrc_n[r] = n; bsrc_c[r] = sl ^ (n & 7);
    bdst[r] = (r * 4 + wave) * 64 * 8;
  }

  // A row pointers: this lane covers rows (wm+l16) and (wm+16+l16),
  // float chunk quad*8..+7 within each 32-wide half of the K-step.
  const float* xr0 = X + (size_t)(m0 + wm + l16) * C_ + quad * 8;
  const float* xr1 = xr0 + (size_t)16 * C_;

  // ---- prologue: B_0 DMA + A_0 register loads
#pragma unroll
  for (int r = 0; r < 4; ++r)
    async_copy16(Wt + (size_t)(n0 + bsrc_n[r]) * C_ + bsrc_c[r] * 8,
                 &Bs[0][bdst[r]]);
  float4 av[8];
  av[0] = *(const float4*)(xr0);       av[1] = *(const float4*)(xr0 + 4);
  av[2] = *(const float4*)(xr0 + 32);  av[3] = *(const float4*)(xr0 + 36);
  av[4] = *(const float4*)(xr1);       av[5] = *(const float4*)(xr1 + 4);
  av[6] = *(const float4*)(xr1 + 32);  av[7] = *(const float4*)(xr1 + 36);

  floatx4 acc[2][4] = {};

  for (int k = 0; k < 32; ++k) {
    const int cur = k & 1, nxt = cur ^ 1;
    // ---- convert A_k in-register: af[ks][mt]
    bf16x8 af[2][2];
    af[0][0] = cvt8(av[0], av[1]);   // ks=0, rows wm+l16
    af[1][0] = cvt8(av[2], av[3]);   // ks=1, rows wm+l16
    af[0][1] = cvt8(av[4], av[5]);   // ks=0, rows wm+16+l16
    af[1][1] = cvt8(av[6], av[7]);   // ks=1, rows wm+16+l16

    __syncthreads();   // drains B_k DMA (issued last iter)

    // ---- issue next iteration's loads (drained only at NEXT barrier)
    if (k < 31) {
      const int kn = (k + 1) * 64;
#pragma unroll
      for (int r = 0; r < 4; ++r)
        async_copy16(Wt + (size_t)(n0 + bsrc_n[r]) * C_ + kn + bsrc_c[r] * 8,
                     &Bs[nxt][bdst[r]]);
      av[0] = *(const float4*)(xr0 + kn);       av[1] = *(const float4*)(xr0 + kn + 4);
      av[2] = *(const float4*)(xr0 + kn + 32);  av[3] = *(const float4*)(xr0 + kn + 36);
      av[4] = *(const float4*)(xr1 + kn);       av[5] = *(const float4*)(xr1 + kn + 4);
      av[6] = *(const float4*)(xr1 + kn + 32);  av[7] = *(const float4*)(xr1 + kn + 36);
    }

    // ---- compute: 16 MFMAs/wave, B frags from swizzled LDS (conflict-free)
#pragma unroll
    for (int ks = 0; ks < 2; ++ks) {
      bf16x8 bfv[4];
#pragma unroll
      for (int nt = 0; nt < 4; ++nt) {
        int n = wn + nt * 16 + l16;
        int c = ks * 4 + quad;
        bfv[nt] = *(const bf16x8*)&Bs[cur][n * 64 + (c ^ (n & 7)) * 8];
      }
#pragma unroll
      for (int mt = 0; mt < 2; ++mt)
#pragma unroll
        for (int nt = 0; nt < 4; ++nt)
          acc[mt][nt] = __builtin_amdgcn_mfma_f32_16x16x32_bf16(
              af[ks][mt], bfv[nt], acc[mt][nt], 0, 0, 0);
    }
  }

  // ---- epilogue: C/D layout col=lane&15, row=quad*4+reg
#pragma unroll
  for (int mt = 0; mt < 2; ++mt)
#pragma unroll
    for (int nt = 0; nt < 4; ++nt)
#pragma unroll
      for (int r = 0; r < 4; ++r) {
        int row = m0 + wm + mt * 16 + quad * 4 + r;
        int col = wn + nt * 16 + l16;
        unsigned short us = f2bf(acc[mt][nt][r]);
        kqv[(size_t)row * N_ + n0 + col] = us;
        if (n0 == 256) {
          int bb = row >> 8, tt = row & 255;
          vT[(size_t)bb * HS_ * T_ + (size_t)col * T_ + tt] = us;
        }
      }
}

// ---------------- Attention: 4 waves/block, 2 waves per 16-row t-tile -------
// Wave (tile, par): handles s-tiles st with st&1==par, packed densely in its
// private P buffer. Partial O (unnormalized) + partial rowsum combined in LDS.
// Tile pairing {x, 15-x}: every block carries an equal 17 units of causal
// work, so every CU gets the same load (old (2x,2x+1) pairing gave 5..28).
__global__ __launch_bounds__(256) void attn_kernel(
    const unsigned short* __restrict__ kqv, const unsigned short* __restrict__ vT,
    float* __restrict__ out) {
  __shared__ unsigned short P[4][16 * 136];  // 17.4 KB, per-wave packed P
  __shared__ float Olds[2][16][132];         // 16.9 KB (pad 132)
  __shared__ float rs1[2][16];

  const int tid  = threadIdx.x;
  const int wave = tid >> 6, lane = tid & 63;
  const int quad = lane >> 4, l16 = lane & 15;
  const int tile = wave >> 1, par = wave & 1;
  const int tt = tile ? (15 - (int)blockIdx.x) : (int)blockIdx.x;  // balanced pair
  const int b  = blockIdx.y;
  const int t0 = tt * 16;
  const float scale = 0.022097086912079612f; // 2048^-0.5
  const unsigned short* kq = kqv + (size_t)b * T_ * N_;

  // k fragments (A operand), rows t0..t0+15
  bf16x8 kf[4];
#pragma unroll
  for (int ks = 0; ks < 4; ++ks)
    kf[ks] = *(const bf16x8*)&kq[(size_t)(t0 + l16) * N_ + ks * 32 + quad * 8];

  const int n_my = ((tt + 1) + (1 - par)) >> 1;  // my s-tile count
  const int npad = (n_my + 1) & ~1;              // padded to even

  float rsum[4] = {0.f, 0.f, 0.f, 0.f};

  // ---- S = k q^T over my s-tiles, exp+mask, pack into P (manual prefetch)
  bf16x8 qf[4];
  if (n_my > 0) {
    const int st = par;
#pragma unroll
    for (int ks = 0; ks < 4; ++ks)
      qf[ks] = *(const bf16x8*)&kq[(size_t)(st * 16 + l16) * N_ + HS_ + ks * 32 + quad * 8];
  }
  for (int j = 0; j < n_my; ++j) {
    bf16x8 qn[4];
    if (j + 1 < n_my) {
      const int st = par + 2 * (j + 1);
#pragma unroll
      for (int ks = 0; ks < 4; ++ks)
        qn[ks] = *(const bf16x8*)&kq[(size_t)(st * 16 + l16) * N_ + HS_ + ks * 32 + quad * 8];
    }
    floatx4 a = {};
#pragma unroll
    for (int ks = 0; ks < 4; ++ks)
      a = __builtin_amdgcn_mfma_f32_16x16x32_bf16(kf[ks], qf[ks], a, 0, 0, 0);
    const int st = par + 2 * j;
    const int scol = st * 16 + l16;
#pragma unroll
    for (int r = 0; r < 4; ++r) {
      int trow = t0 + quad * 4 + r;
      float p = (scol <= trow) ? __expf(a[r] * scale) : 0.f;
      rsum[r] += p;
      P[wave][(quad * 4 + r) * 136 + j * 16 + l16] = f2bf(p);
    }
#pragma unroll
    for (int ks = 0; ks < 4; ++ks) qf[ks] = qn[ks];
  }
  if (npad > n_my) {  // zero-fill the odd tail tile
#pragma unroll
    for (int r = 0; r < 4; ++r)
      P[wave][(quad * 4 + r) * 136 + n_my * 16 + l16] = 0;
  }
  // row sums: reduce across the 16 lanes of each quad
#pragma unroll
  for (int m = 1; m < 16; m <<= 1)
#pragma unroll
    for (int r = 0; r < 4; ++r)
      rsum[r] += __shfl_xor(rsum[r], m, 64);

  // ---- O_partial = P @ V over packed k-steps (manual prefetch)
  floatx4 oacc[8] = {};
  const unsigned short* vb = vT + (size_t)b * HS_ * T_;
  const int nks = npad >> 1;
  const int sb_off = (quad >> 1);        // which packed 16-tile inside 32-k
  const int sb_lo  = (quad & 1) * 8;
  bf16x8 bv[8]; bf16x8 pa;
  if (nks > 0) {
    int st = par + 2 * (0 + sb_off);
    int sbase = st * 16 + sb_lo;
    pa = *(const bf16x8*)&P[wave][l16 * 136 + 0 * 32 + quad * 8];
#pragma unroll
    for (int nt = 0; nt < 8; ++nt)
      bv[nt] = *(const bf16x8*)&vb[(size_t)(nt * 16 + l16) * T_ + sbase];
  }
  for (int ks2 = 0; ks2 < nks; ++ks2) {
    bf16x8 bvn[8]; bf16x8 pan;
    if (ks2 + 1 < nks) {
      int jt = 2 * (ks2 + 1) + sb_off;
      int st = par + 2 * jt;
      int sbase = st * 16 + sb_lo;
      pan = *(const bf16x8*)&P[wave][l16 * 136 + (ks2 + 1) * 32 + quad * 8];
#pragma unroll
      for (int nt = 0; nt < 8; ++nt)
        bvn[nt] = *(const bf16x8*)&vb[(size_t)(nt * 16 + l16) * T_ + sbase];
    }
#pragma unroll
    for (int nt = 0; nt < 8; ++nt)
      oacc[nt] = __builtin_amdgcn_mfma_f32_16x16x32_bf16(pa, bv[nt], oacc[nt], 0, 0, 0);
    pa = pan;
#pragma unroll
    for (int nt = 0; nt < 8; ++nt) bv[nt] = bvn[nt];
  }

  // ---- combine partials across the two parity waves of each tile
  if (par == 1) {
#pragma unroll
    for (int nt = 0; nt < 8; ++nt)
#pragma unroll
      for (int r = 0; r < 4; ++r)
        Olds[tile][quad * 4 + r][nt * 16 + l16] = oacc[nt][r];
    if (l16 == 0) {
#pragma unroll
      for (int r = 0; r < 4; ++r) rs1[tile][quad * 4 + r] = rsum[r];
    }
  }
  __syncthreads();
  if (par == 0) {
    float inv[4];
#pragma unroll
    for (int r = 0; r < 4; ++r)
      inv[r] = 1.f / (rsum[r] + rs1[tile][quad * 4 + r]);
    float* ob = out + ((size_t)b * T_ + t0) * HS_;
#pragma unroll
    for (int nt = 0; nt < 8; ++nt)
#pragma unroll
      for (int r = 0; r < 4; ++r) {
        int row = quad * 4 + r;
        ob[(size_t)row * HS_ + nt * 16 + l16] =
            (oacc[nt][r] + Olds[tile][row][nt * 16 + l16]) * inv[r];
      }
  }
}

extern "C" void kernel_launch(void* const* d_in, const int* in_sizes, int n_in,
                              void* d_out, int out_size, void* d_ws, size_t ws_size,
                              hipStream_t stream) {
  const float* x  = (const float*)d_in[0];
  const float* Wk = (const float*)d_in[1];
  const float* Wq = (const float*)d_in[2];
  const float* Wv = (const float*)d_in[3];
  float* out = (float*)d_out;

  char* ws = (char*)d_ws;
  unsigned short* Wt  = (unsigned short*)(ws);                        // 1.5 MB
  unsigned short* kqv = (unsigned short*)(ws + 1572864);              // 12 MB
  unsigned short* vT  = (unsigned short*)(ws + 1572864 + 12582912);   // 4 MB

  hipLaunchKernelGGL(wt_kernel, dim3(64, 4, 3), dim3(256), 0, stream, Wk, Wq, Wv, Wt);
  hipLaunchKernelGGL(qkv_gemm, dim3(768), dim3(256), 0, stream, x, Wt, kqv, vT);
  hipLaunchKernelGGL(attn_kernel, dim3(8, 64), dim3(256), 0, stream, kqv, vT, out);
}

// Round 3
// 241.758 us; speedup vs baseline: 1.1989x; 1.1696x over previous
//
#include <hip/hip_runtime.h>
#include <hip/hip_bf16.h>
#include <cstdint>
#include <cstddef>

#define B_  64
#define T_  256
#define C_  2048
#define HS_ 128
#define N_  384

typedef __bf16 bf16x8 __attribute__((ext_vector_type(8)));
typedef float  floatx4 __attribute__((ext_vector_type(4)));

__device__ __forceinline__ unsigned short f2bf_rne(float f) {
  union { float f; unsigned int u; } v; v.f = f;
  unsigned int r = v.u + 0x7fffu + ((v.u >> 16) & 1u);
  return (unsigned short)(r >> 16);
}
__device__ __forceinline__ unsigned short f2bf(float f) {
  union { float f; unsigned int u; } v; v.f = f;
  return (unsigned short)((v.u + 0x8000u) >> 16);
}

__device__ __forceinline__ void async_copy16(const void* g, void* l) {
  __builtin_amdgcn_global_load_lds(
      (const __attribute__((address_space(1))) unsigned int*)g,
      (__attribute__((address_space(3))) unsigned int*)l, 16, 0, 0);
}

// ---------------- Weight transpose + bf16 cast: Wt[w*128+h][c] = W_w[c][h] ---
__global__ __launch_bounds__(256) void wt_kernel(
    const float* __restrict__ Wk, const float* __restrict__ Wq,
    const float* __restrict__ Wv, unsigned short* __restrict__ Wt) {
  __shared__ float tile[32][33];
  const int w  = blockIdx.z;
  const int c0 = blockIdx.x * 32;
  const int h0 = blockIdx.y * 32;
  const float* W = (w == 0) ? Wk : (w == 1) ? Wq : Wv;
  const int tx = threadIdx.x & 31, ty = threadIdx.x >> 5;
#pragma unroll
  for (int i = 0; i < 32; i += 8)
    tile[ty + i][tx] = W[(size_t)(c0 + ty + i) * HS_ + h0 + tx];
  __syncthreads();
#pragma unroll
  for (int i = 0; i < 32; i += 8) {
    int hh = ty + i, cc = tx;
    Wt[(size_t)(w * HS_ + h0 + hh) * C_ + c0 + cc] = f2bf_rne(tile[cc][hh]);
  }
}

// ---------------- QKV GEMM: 128m x 96n tile, BK=64 (m93-rung geometry) ------
// 4 waves, wave tile 64x48 (4m x 3n frags, 12 independent acc chains).
// Grid = 128 m-tiles x 4 n-tiles = 512 blocks = exactly 2/CU (no tail).
// Proven round-0 machinery kept verbatim: coalesced float4 A loads ->
// in-register f2bf -> pad-72 As staging; B via global_load_lds with xor
// swizzle; ONE barrier per K-step; DMA + A loads issued right after the
// barrier get a full iteration of latency cover (the vmcnt(0) the compiler
// inserts before the av use also drains the DMA just before the barrier).
__global__ __launch_bounds__(256, 2) void qkv_gemm(
    const float* __restrict__ X, const unsigned short* __restrict__ Wt,
    unsigned short* __restrict__ kqv, unsigned short* __restrict__ vT) {
  __shared__ unsigned short As[2][128 * 72];  // 2 x 18 KB (pad 72 vs 64)
  __shared__ unsigned short Bs[2][96 * 64];   // 2 x 12 KB (xor-swizzled)

  const int tid  = threadIdx.x;
  const int wave = tid >> 6, lane = tid & 63;
  const int quad = lane >> 4, l16 = lane & 15;

  // m = bid&127, nb = bid>>7: the 4 n-variants of one m-panel are bid,
  // bid+128, ... -> all congruent mod 8 -> same XCD -> A-panel L2 reuse.
  const int bid = blockIdx.x;
  const int m0  = (bid & 127) * 128;
  const int n0  = (bid >> 7) * 96;
  const int wm  = (wave >> 1) * 64;   // {0, 64}
  const int wn  = (wave & 1) * 48;    // {0, 48}

  // B DMA source mapping (xor swizzle applied on the global-address side).
  // 96 rows x 8 chunks = 768 slots = 3 per thread.
  int bsrc_n[3], bsrc_c[3], bdst[3];
#pragma unroll
  for (int r = 0; r < 3; ++r) {
    int slot = r * 256 + tid;
    int n = slot >> 3, sl = slot & 7;
    bsrc_n[r] = n; bsrc_c[r] = sl ^ (n & 7);
    bdst[r] = (r * 256 + wave * 64) * 8;   // wave-uniform base + lane*16B
  }

  // A staging: 128 rows x 16 float4-chunks = 2048 slots = 8 per thread.
  const int arow = tid >> 4;     // 0..15 (+ r*16)
  const int achk = tid & 15;     // float4 chunk in the 64-wide K-step

  // ---- prologue: B_0 DMA + A_0 global loads
#pragma unroll
  for (int r = 0; r < 3; ++r)
    async_copy16(Wt + (size_t)(n0 + bsrc_n[r]) * C_ + bsrc_c[r] * 8,
                 &Bs[0][bdst[r]]);
  float4 av[8];
#pragma unroll
  for (int r = 0; r < 8; ++r)
    av[r] = *(const float4*)(X + (size_t)(m0 + arow + r * 16) * C_ + achk * 4);

  floatx4 acc[4][3] = {};

  for (int k = 0; k < 32; ++k) {
    const int cur = k & 1, nxt = cur ^ 1;
    // ---- convert & store A_k (forces vmcnt drain of av + this buf's DMA)
#pragma unroll
    for (int r = 0; r < 8; ++r) {
      ushort4 b4;
      b4.x = f2bf(av[r].x); b4.y = f2bf(av[r].y);
      b4.z = f2bf(av[r].z); b4.w = f2bf(av[r].w);
      *(ushort4*)&As[cur][(arow + r * 16) * 72 + achk * 4] = b4;
    }
    __syncthreads();   // As[cur] stores + Bs[cur] DMA now visible

    // ---- issue next iteration's loads (a full iteration of latency cover)
    if (k < 31) {
      const int kn = (k + 1) * 64;
#pragma unroll
      for (int r = 0; r < 3; ++r)
        async_copy16(Wt + (size_t)(n0 + bsrc_n[r]) * C_ + kn + bsrc_c[r] * 8,
                     &Bs[nxt][bdst[r]]);
#pragma unroll
      for (int r = 0; r < 8; ++r)
        av[r] = *(const float4*)(X + (size_t)(m0 + arow + r * 16) * C_ + kn + achk * 4);
    }

    // ---- compute: 24 MFMAs/wave (2 ks x 4m x 3n), 12 independent chains
#pragma unroll
    for (int ks = 0; ks < 2; ++ks) {
      bf16x8 af[4], bfv[3];
#pragma unroll
      for (int mt = 0; mt < 4; ++mt)
        af[mt] = *(const bf16x8*)&As[cur][(wm + mt * 16 + l16) * 72 + ks * 32 + quad * 8];
#pragma unroll
      for (int nt = 0; nt < 3; ++nt) {
        int n = wn + nt * 16 + l16;
        int c = ks * 4 + quad;
        bfv[nt] = *(const bf16x8*)&Bs[cur][n * 64 + (c ^ (n & 7)) * 8];
      }
#pragma unroll
      for (int mt = 0; mt < 4; ++mt)
#pragma unroll
        for (int nt = 0; nt < 3; ++nt)
          acc[mt][nt] = __builtin_amdgcn_mfma_f32_16x16x32_bf16(
              af[mt], bfv[nt], acc[mt][nt], 0, 0, 0);
    }
  }

  // ---- epilogue: C/D layout col=lane&15, row=quad*4+reg
#pragma unroll
  for (int mt = 0; mt < 4; ++mt)
#pragma unroll
    for (int nt = 0; nt < 3; ++nt)
#pragma unroll
      for (int r = 0; r < 4; ++r) {
        int row = m0 + wm + mt * 16 + quad * 4 + r;
        int col = n0 + wn + nt * 16 + l16;
        unsigned short us = f2bf(acc[mt][nt][r]);
        kqv[(size_t)row * N_ + col] = us;
        if (col >= 256) {   // V region -> also store transposed
          int bb = row >> 8, tt = row & 255;
          vT[(size_t)bb * HS_ * T_ + (size_t)(col - 256) * T_ + tt] = us;
        }
      }
}

// ---------------- Attention: 4 waves/block, 2 waves per 16-row t-tile -------
// Wave (tile, par): handles s-tiles st with st&1==par, packed densely in its
// private P buffer. Partial O (unnormalized) + partial rowsum combined in LDS.
// Tile pairing {x, 15-x}: every block carries an equal 17 units of causal
// work, so every CU gets the same load.
__global__ __launch_bounds__(256) void attn_kernel(
    const unsigned short* __restrict__ kqv, const unsigned short* __restrict__ vT,
    float* __restrict__ out) {
  __shared__ unsigned short P[4][16 * 136];  // 17.4 KB, per-wave packed P
  __shared__ float Olds[2][16][132];         // 16.9 KB (pad 132)
  __shared__ float rs1[2][16];

  const int tid  = threadIdx.x;
  const int wave = tid >> 6, lane = tid & 63;
  const int quad = lane >> 4, l16 = lane & 15;
  const int tile = wave >> 1, par = wave & 1;
  const int tt = tile ? (15 - (int)blockIdx.x) : (int)blockIdx.x;  // balanced pair
  const int b  = blockIdx.y;
  const int t0 = tt * 16;
  const float scale = 0.022097086912079612f; // 2048^-0.5
  const unsigned short* kq = kqv + (size_t)b * T_ * N_;

  // k fragments (A operand), rows t0..t0+15
  bf16x8 kf[4];
#pragma unroll
  for (int ks = 0; ks < 4; ++ks)
    kf[ks] = *(const bf16x8*)&kq[(size_t)(t0 + l16) * N_ + ks * 32 + quad * 8];

  const int n_my = ((tt + 1) + (1 - par)) >> 1;  // my s-tile count
  const int npad = (n_my + 1) & ~1;              // padded to even

  float rsum[4] = {0.f, 0.f, 0.f, 0.f};

  // ---- S = k q^T over my s-tiles, exp+mask, pack into P (manual prefetch)
  bf16x8 qf[4];
  if (n_my > 0) {
    const int st = par;
#pragma unroll
    for (int ks = 0; ks < 4; ++ks)
      qf[ks] = *(const bf16x8*)&kq[(size_t)(st * 16 + l16) * N_ + HS_ + ks * 32 + quad * 8];
  }
  for (int j = 0; j < n_my; ++j) {
    bf16x8 qn[4];
    if (j + 1 < n_my) {
      const int st = par + 2 * (j + 1);
#pragma unroll
      for (int ks = 0; ks < 4; ++ks)
        qn[ks] = *(const bf16x8*)&kq[(size_t)(st * 16 + l16) * N_ + HS_ + ks * 32 + quad * 8];
    }
    floatx4 a = {};
#pragma unroll
    for (int ks = 0; ks < 4; ++ks)
      a = __builtin_amdgcn_mfma_f32_16x16x32_bf16(kf[ks], qf[ks], a, 0, 0, 0);
    const int st = par + 2 * j;
    const int scol = st * 16 + l16;
#pragma unroll
    for (int r = 0; r < 4; ++r) {
      int trow = t0 + quad * 4 + r;
      float p = (scol <= trow) ? __expf(a[r] * scale) : 0.f;
      rsum[r] += p;
      P[wave][(quad * 4 + r) * 136 + j * 16 + l16] = f2bf(p);
    }
#pragma unroll
    for (int ks = 0; ks < 4; ++ks) qf[ks] = qn[ks];
  }
  if (npad > n_my) {  // zero-fill the odd tail tile
#pragma unroll
    for (int r = 0; r < 4; ++r)
      P[wave][(quad * 4 + r) * 136 + n_my * 16 + l16] = 0;
  }
  // row sums: reduce across the 16 lanes of each quad
#pragma unroll
  for (int m = 1; m < 16; m <<= 1)
#pragma unroll
    for (int r = 0; r < 4; ++r)
      rsum[r] += __shfl_xor(rsum[r], m, 64);

  // ---- O_partial = P @ V over packed k-steps (manual prefetch)
  floatx4 oacc[8] = {};
  const unsigned short* vb = vT + (size_t)b * HS_ * T_;
  const int nks = npad >> 1;
  const int sb_off = (quad >> 1);        // which packed 16-tile inside 32-k
  const int sb_lo  = (quad & 1) * 8;
  bf16x8 bv[8]; bf16x8 pa;
  if (nks > 0) {
    int st = par + 2 * (0 + sb_off);
    int sbase = st * 16 + sb_lo;
    pa = *(const bf16x8*)&P[wave][l16 * 136 + 0 * 32 + quad * 8];
#pragma unroll
    for (int nt = 0; nt < 8; ++nt)
      bv[nt] = *(const bf16x8*)&vb[(size_t)(nt * 16 + l16) * T_ + sbase];
  }
  for (int ks2 = 0; ks2 < nks; ++ks2) {
    bf16x8 bvn[8]; bf16x8 pan;
    if (ks2 + 1 < nks) {
      int jt = 2 * (ks2 + 1) + sb_off;
      int st = par + 2 * jt;
      int sbase = st * 16 + sb_lo;
      pan = *(const bf16x8*)&P[wave][l16 * 136 + (ks2 + 1) * 32 + quad * 8];
#pragma unroll
      for (int nt = 0; nt < 8; ++nt)
        bvn[nt] = *(const bf16x8*)&vb[(size_t)(nt * 16 + l16) * T_ + sbase];
    }
#pragma unroll
    for (int nt = 0; nt < 8; ++nt)
      oacc[nt] = __builtin_amdgcn_mfma_f32_16x16x32_bf16(pa, bv[nt], oacc[nt], 0, 0, 0);
    pa = pan;
#pragma unroll
    for (int nt = 0; nt < 8; ++nt) bv[nt] = bvn[nt];
  }

  // ---- combine partials across the two parity waves of each tile
  if (par == 1) {
#pragma unroll
    for (int nt = 0; nt < 8; ++nt)
#pragma unroll
      for (int r = 0; r < 4; ++r)
        Olds[tile][quad * 4 + r][nt * 16 + l16] = oacc[nt][r];
    if (l16 == 0) {
#pragma unroll
      for (int r = 0; r < 4; ++r) rs1[tile][quad * 4 + r] = rsum[r];
    }
  }
  __syncthreads();
  if (par == 0) {
    float inv[4];
#pragma unroll
    for (int r = 0; r < 4; ++r)
      inv[r] = 1.f / (rsum[r] + rs1[tile][quad * 4 + r]);
    float* ob = out + ((size_t)b * T_ + t0) * HS_;
#pragma unroll
    for (int nt = 0; nt < 8; ++nt)
#pragma unroll
      for (int r = 0; r < 4; ++r) {
        int row = quad * 4 + r;
        ob[(size_t)row * HS_ + nt * 16 + l16] =
            (oacc[nt][r] + Olds[tile][row][nt * 16 + l16]) * inv[r];
      }
  }
}

extern "C" void kernel_launch(void* const* d_in, const int* in_sizes, int n_in,
                              void* d_out, int out_size, void* d_ws, size_t ws_size,
                              hipStream_t stream) {
  const float* x  = (const float*)d_in[0];
  const float* Wk = (const float*)d_in[1];
  const float* Wq = (const float*)d_in[2];
  const float* Wv = (const float*)d_in[3];
  float* out = (float*)d_out;

  char* ws = (char*)d_ws;
  unsigned short* Wt  = (unsigned short*)(ws);                        // 1.5 MB
  unsigned short* kqv = (unsigned short*)(ws + 1572864);              // 12 MB
  unsigned short* vT  = (unsigned short*)(ws + 1572864 + 12582912);   // 4 MB

  hipLaunchKernelGGL(wt_kernel, dim3(64, 4, 3), dim3(256), 0, stream, Wk, Wq, Wv, Wt);
  hipLaunchKernelGGL(qkv_gemm, dim3(512), dim3(256), 0, stream, x, Wt, kqv, vT);
  hipLaunchKernelGGL(attn_kernel, dim3(8, 64), dim3(256), 0, stream, kqv, vT, out);
}